// Round 1
// baseline (124.447 us; speedup 1.0000x reference)
//
#include <hip/hip_runtime.h>
#include <math.h>

#define BB 4
#define NN 1024
#define HH 8
#define NROW (BB*NN)  // 4096

typedef short s8v __attribute__((ext_vector_type(8)));
typedef float f4v __attribute__((ext_vector_type(4)));

__device__ __forceinline__ short bf16rne(float f) {
    unsigned u = __float_as_uint(f);
    u += 0x7FFF + ((u >> 16) & 1u);
    return (short)(u >> 16);
}

// ---------------------------------------------------------------------------
// K1: g = h@W (8 rows/block, 512 blocks) + fused e_i/e_j via shfl-xor reduce.
// NEW: instead of raw e_i/e_j, store exp tables for the separable-max trick:
//   exp(lrelu(ei+ej)) == max(exp(ei)*exp(ej), exp(.2ei)*exp(.2ej))
// EFi/EFj: [(b*N+n)*16 + 2h + {0,1}] = {exp(e), exp(.2e)}
// EFjt:    [((b*8+h)*2 + {0,1})*N + n] (transposed, for k_out staging)
// ---------------------------------------------------------------------------
__global__ __launch_bounds__(256) void k_gemm_ei(const float* __restrict__ hm,
                                                 const float* __restrict__ W,
                                                 const float* __restrict__ aw,
                                                 float* __restrict__ g,
                                                 float* __restrict__ EFi,
                                                 float* __restrict__ EFj,
                                                 float* __restrict__ EFjt) {
    __shared__ __align__(16) float hs[8][256];
    __shared__ float aws[64];
    const int row0 = blockIdx.x * 8;
    const int t = threadIdx.x;
    if (t < 64) aws[t] = aw[t];
    const float4* h4 = (const float4*)(hm + row0 * 256);
    float4* hs4 = (float4*)&hs[0][0];
    hs4[t] = h4[t];
    hs4[t + 256] = h4[t + 256];
    __syncthreads();

    float acc[8];
#pragma unroll
    for (int r = 0; r < 8; ++r) acc[r] = 0.f;
    for (int k4 = 0; k4 < 64; ++k4) {
        const float w0 = W[(4 * k4 + 0) * 256 + t];
        const float w1 = W[(4 * k4 + 1) * 256 + t];
        const float w2 = W[(4 * k4 + 2) * 256 + t];
        const float w3 = W[(4 * k4 + 3) * 256 + t];
#pragma unroll
        for (int r = 0; r < 8; ++r) {
            const float4 hv = *(const float4*)&hs[r][4 * k4];  // broadcast read
            acc[r] = fmaf(hv.x, w0, acc[r]);
            acc[r] = fmaf(hv.y, w1, acc[r]);
            acc[r] = fmaf(hv.z, w2, acc[r]);
            acc[r] = fmaf(hv.w, w3, acc[r]);
        }
    }
    const int d = t & 31, hh = t >> 5;
    const int b = row0 >> 10;
#pragma unroll
    for (int r = 0; r < 8; ++r) {
        g[(row0 + r) * 256 + t] = acc[r];
        float vi = acc[r] * aws[d];
        float vj = acc[r] * aws[32 + d];
#pragma unroll
        for (int mm = 1; mm < 32; mm <<= 1) {
            vi += __shfl_xor(vi, mm);
            vj += __shfl_xor(vj, mm);
        }
        if (d == 0) {
            const int row = row0 + r;
            const float Ei = __expf(vi), Fi = __expf(0.2f * vi);
            const float Ej = __expf(vj), Fj = __expf(0.2f * vj);
            *(float2*)&EFi[(size_t)row * 16 + hh * 2] = make_float2(Ei, Fi);
            *(float2*)&EFj[(size_t)row * 16 + hh * 2] = make_float2(Ej, Fj);
            const int n = row & (NN - 1);
            EFjt[((size_t)(b * 8 + hh) * 2 + 0) * NN + n] = Ej;
            EFjt[((size_t)(b * 8 + hh) * 2 + 1) * NN + n] = Fj;
        }
    }
}

// ---------------------------------------------------------------------------
// K2: column-sum partials ps[ic][(b*N+j)*8+h] = sum over i-chunk of
//     adj[b,i,j]*max(Ei*Ej, Fi*Fj).  512 blocks = b x 16 j-chunks x 8 i-chunks.
//     No transcendentals in the hot loop: 2 mul + 1 max + 1 fma per elem.
// ---------------------------------------------------------------------------
__global__ __launch_bounds__(256) void k_s(const float* __restrict__ adj,
                                           const float* __restrict__ EFi,
                                           const float* __restrict__ EFj,
                                           float* __restrict__ ps) {
    __shared__ __align__(16) float eis[128 * 16];  // 8KB: {E,F} x 8h per i
    __shared__ float sp[4][8][64];
    const int bx = blockIdx.x;
    const int b = bx >> 7, jc = (bx >> 3) & 15, ic = bx & 7;
    const int j0 = jc * 64, i0 = ic * 128;
    const int t = threadIdx.x;

    const float4* src4 = (const float4*)(EFi + (size_t)(b * NN + i0) * 16);
    ((float4*)eis)[t] = src4[t];
    ((float4*)eis)[t + 256] = src4[t + 256];

    const int ii = t >> 6, jj = t & 63;
    // per-thread E/F for its j column, all 8 heads (direct from global, L2-hit)
    const float* ej = EFj + (size_t)(b * NN + j0 + jj) * 16;
    const float4 f0 = *(const float4*)&ej[0];
    const float4 f1 = *(const float4*)&ej[4];
    const float4 f2 = *(const float4*)&ej[8];
    const float4 f3 = *(const float4*)&ej[12];
    const float ejE0 = f0.x, ejF0 = f0.y, ejE1 = f0.z, ejF1 = f0.w;
    const float ejE2 = f1.x, ejF2 = f1.y, ejE3 = f1.z, ejF3 = f1.w;
    const float ejE4 = f2.x, ejF4 = f2.y, ejE5 = f2.z, ejF5 = f2.w;
    const float ejE6 = f3.x, ejF6 = f3.y, ejE7 = f3.z, ejF7 = f3.w;
    __syncthreads();

    float s0 = 0.f, s1 = 0.f, s2 = 0.f, s3 = 0.f;
    float s4 = 0.f, s5 = 0.f, s6 = 0.f, s7 = 0.f;
    const float* adjp = adj + (size_t)b * NN * NN + j0 + jj;
    for (int i = ii; i < 128; i += 4) {
        const float a = adjp[(size_t)(i0 + i) * NN];
        const float4 x0 = *(const float4*)&eis[i * 16];      // broadcast reads
        const float4 x1 = *(const float4*)&eis[i * 16 + 4];
        const float4 x2 = *(const float4*)&eis[i * 16 + 8];
        const float4 x3 = *(const float4*)&eis[i * 16 + 12];
        s0 = fmaf(a, fmaxf(x0.x * ejE0, x0.y * ejF0), s0);
        s1 = fmaf(a, fmaxf(x0.z * ejE1, x0.w * ejF1), s1);
        s2 = fmaf(a, fmaxf(x1.x * ejE2, x1.y * ejF2), s2);
        s3 = fmaf(a, fmaxf(x1.z * ejE3, x1.w * ejF3), s3);
        s4 = fmaf(a, fmaxf(x2.x * ejE4, x2.y * ejF4), s4);
        s5 = fmaf(a, fmaxf(x2.z * ejE5, x2.w * ejF5), s5);
        s6 = fmaf(a, fmaxf(x3.x * ejE6, x3.y * ejF6), s6);
        s7 = fmaf(a, fmaxf(x3.z * ejE7, x3.w * ejF7), s7);
    }
    sp[ii][0][jj] = s0; sp[ii][1][jj] = s1; sp[ii][2][jj] = s2; sp[ii][3][jj] = s3;
    sp[ii][4][jj] = s4; sp[ii][5][jj] = s5; sp[ii][6][jj] = s6; sp[ii][7][jj] = s7;
    __syncthreads();
#pragma unroll
    for (int k = 0; k < 2; ++k) {
        const int idx = t * 2 + k;
        const int jjo = idx >> 3, h = idx & 7;
        const float s = sp[0][h][jjo] + sp[1][h][jjo] + sp[2][h][jjo] + sp[3][h][jjo];
        ps[ic * (NROW * 8) + (b * NN + j0 + jjo) * 8 + h] = s;
    }
}

// ---------------------------------------------------------------------------
// K3: rs = 1/sum(ps); Gt[b][h][jt(32)][d(32)][jj(32)] = bf16(g[j][h,d] * rs)
// ---------------------------------------------------------------------------
__global__ __launch_bounds__(256) void k_prep(const float* __restrict__ ps,
                                              const float* __restrict__ g,
                                              short* __restrict__ Gt) {
    __shared__ float rss[16][8];
    const int bx = blockIdx.x;
    const int b = bx >> 6, j0 = (bx & 63) * 16;
    const int t = threadIdx.x;
    if (t < 128) {
        const int jj = t >> 3, h = t & 7;
        float s = 0.f;
#pragma unroll
        for (int ic = 0; ic < 8; ++ic)
            s += ps[ic * (NROW * 8) + (b * NN + j0 + jj) * 8 + h];
        rss[jj][h] = 1.0f / s;
    }
    __syncthreads();
    const int h = t >> 5, d = t & 31;
    unsigned short v16[16];
#pragma unroll
    for (int r = 0; r < 16; ++r) {
        const float val = g[(size_t)(b * NN + j0 + r) * 256 + t] * rss[r][h];
        v16[r] = (unsigned short)bf16rne(val);
    }
    const int jt = j0 >> 5, jj0 = j0 & 31;
    short* dst = Gt + ((size_t)((b * 8 + h) * 32 + jt)) * 1024 + d * 32 + jj0;
    uint4 w0, w1;
    w0.x = (unsigned)v16[0] | ((unsigned)v16[1] << 16);
    w0.y = (unsigned)v16[2] | ((unsigned)v16[3] << 16);
    w0.z = (unsigned)v16[4] | ((unsigned)v16[5] << 16);
    w0.w = (unsigned)v16[6] | ((unsigned)v16[7] << 16);
    w1.x = (unsigned)v16[8] | ((unsigned)v16[9] << 16);
    w1.y = (unsigned)v16[10] | ((unsigned)v16[11] << 16);
    w1.z = (unsigned)v16[12] | ((unsigned)v16[13] << 16);
    w1.w = (unsigned)v16[14] | ((unsigned)v16[15] << 16);
    *(uint4*)dst = w0;
    *(uint4*)(dst + 8) = w1;
}

// ---------------------------------------------------------------------------
// K4: MFMA contraction. 512 blocks = (h-half, b, i-tile16); 4 waves, 1 head
// each. A generated in registers in A-frag layout (m=lane&15, k=quad*8+e).
// NEW: A-elem = adj * max(Ei*Ej, Fi*Fj)  (no exp, no lrelu), packed to bf16
// via v_cvt_pk_bf16_f32 (1 inst per 2 elems). All tiles in NAMED regs
// (scratch fix from r5 preserved).
// ---------------------------------------------------------------------------
__global__ __launch_bounds__(256) void k_out_mfma(const float* __restrict__ adj,
                                                  const short* __restrict__ Gt,
                                                  const float* __restrict__ EFi,
                                                  const float* __restrict__ EFjt,
                                                  float* __restrict__ out) {
    __shared__ short gts[4][4][32][40];  // 40KB: [h-local][jt-local][d][jj+pad]
    __shared__ float ejt[4][2][128];     // 4KB: [h-local][{E,F}][j within superstep]
    const int bx = blockIdx.x;
    const int hs = bx >> 8, b = (bx >> 6) & 3, i0 = (bx & 63) * 16;
    const int t = threadIdx.x;
    const int wave = t >> 6, lane = t & 63;
    const int m = lane & 15, q = lane >> 4;
    const int h = hs * 4 + wave;  // this wave's head

    const float2 eif = *(const float2*)&EFi[(size_t)(b * NN + i0 + m) * 16 + h * 2];
    const float EiV = eif.x, FiV = eif.y;
    f4v acc0 = {0.f, 0.f, 0.f, 0.f}, acc1 = {0.f, 0.f, 0.f, 0.f};

    const float* adjrow = adj + (size_t)b * NN * NN + (size_t)(i0 + m) * NN;
    const float4* gtg4 = (const float4*)Gt;  // 8 shorts per float4
    const float4* ejt4 = (const float4*)(EFjt + (size_t)b * 8 * 2 * NN);

    for (int s = 0; s < 8; ++s) {
        // ---- issue Gt loads (named regs g0..g7) + adj loads (a0..a7) + ej
        float4 g0, g1, g2, g3, g4, g5, g6, g7;
#define LG(k)                                                                     \
        {                                                                         \
            const int u = t + 256 * (k);                                          \
            g##k = gtg4[(size_t)(b * 8 + hs * 4 + (u >> 9)) * 4096 + s * 512 +    \
                        (u & 511)];                                               \
        }
        LG(0) LG(1) LG(2) LG(3) LG(4) LG(5) LG(6) LG(7)
#undef LG
        f4v a0, a1, a2, a3, a4, a5, a6, a7;
#define LA(k2, lt, half)                                                          \
        a##k2 = *(const f4v*)&adjrow[s * 128 + (lt) * 32 + q * 8 + (half) * 4];
        LA(0, 0, 0) LA(1, 0, 1) LA(2, 1, 0) LA(3, 1, 1)
        LA(4, 2, 0) LA(5, 2, 1) LA(6, 3, 0) LA(7, 3, 1)
#undef LA
        // all 256 threads: one float4 of EFjt ({E,F} rows x 4 heads x 32 f4)
        const float4 ev =
            ejt4[(size_t)((hs * 4 + (t >> 6)) * 2 + ((t >> 5) & 1)) * 256 +
                 s * 32 + (t & 31)];
        __syncthreads();  // prior super's LDS reads done
#define SG(k)                                                                     \
        {                                                                         \
            const int u = t + 256 * (k);                                          \
            char* dstp = (char*)gts + (u >> 9) * 10240 + ((u >> 7) & 3) * 2560 +  \
                         ((u >> 2) & 31) * 80 + (u & 3) * 16;                     \
            *(float4*)dstp = g##k;                                                \
        }
        SG(0) SG(1) SG(2) SG(3) SG(4) SG(5) SG(6) SG(7)
#undef SG
        *(float4*)&ejt[t >> 6][(t >> 5) & 1][(t & 31) * 4] = ev;
        __syncthreads();  // LDS tile visible

        // ---- compute: 4 j-steps of 32, A built in named regs only
#define LT(lt, aA, aB)                                                            \
        {                                                                         \
            const f4v ejA = *(const f4v*)&ejt[wave][0][(lt) * 32 + q * 8];        \
            const f4v ejB = *(const f4v*)&ejt[wave][0][(lt) * 32 + q * 8 + 4];    \
            const f4v fjA = *(const f4v*)&ejt[wave][1][(lt) * 32 + q * 8];        \
            const f4v fjB = *(const f4v*)&ejt[wave][1][(lt) * 32 + q * 8 + 4];    \
            const float p0 = aA[0] * fmaxf(EiV * ejA[0], FiV * fjA[0]);           \
            const float p1 = aA[1] * fmaxf(EiV * ejA[1], FiV * fjA[1]);           \
            const float p2 = aA[2] * fmaxf(EiV * ejA[2], FiV * fjA[2]);           \
            const float p3 = aA[3] * fmaxf(EiV * ejA[3], FiV * fjA[3]);           \
            const float p4 = aB[0] * fmaxf(EiV * ejB[0], FiV * fjB[0]);           \
            const float p5 = aB[1] * fmaxf(EiV * ejB[1], FiV * fjB[1]);           \
            const float p6 = aB[2] * fmaxf(EiV * ejB[2], FiV * fjB[2]);           \
            const float p7 = aB[3] * fmaxf(EiV * ejB[3], FiV * fjB[3]);           \
            unsigned w0, w1, w2, w3;                                              \
            asm("v_cvt_pk_bf16_f32 %0, %1, %2" : "=v"(w0) : "v"(p0), "v"(p1));    \
            asm("v_cvt_pk_bf16_f32 %0, %1, %2" : "=v"(w1) : "v"(p2), "v"(p3));    \
            asm("v_cvt_pk_bf16_f32 %0, %1, %2" : "=v"(w2) : "v"(p4), "v"(p5));    \
            asm("v_cvt_pk_bf16_f32 %0, %1, %2" : "=v"(w3) : "v"(p6), "v"(p7));    \
            union { unsigned u[4]; s8v v; } Au;                                   \
            Au.u[0] = w0; Au.u[1] = w1; Au.u[2] = w2; Au.u[3] = w3;               \
            const s8v A = Au.v;                                                   \
            const s8v B0 = *(const s8v*)&gts[wave][lt][m][q * 8];                 \
            const s8v B1 = *(const s8v*)&gts[wave][lt][m + 16][q * 8];            \
            acc0 = __builtin_amdgcn_mfma_f32_16x16x32_bf16(A, B0, acc0, 0, 0, 0); \
            acc1 = __builtin_amdgcn_mfma_f32_16x16x32_bf16(A, B1, acc1, 0, 0, 0); \
        }
        LT(0, a0, a1) LT(1, a2, a3) LT(2, a4, a5) LT(3, a6, a7)
#undef LT
    }

    // ---- epilogue: C layout col=lane&15, row=quad*4+reg
    float* op = out + (size_t)(b * NN + i0) * 256;
#pragma unroll
    for (int r = 0; r < 4; ++r) {
        const int row = q * 4 + r;
        op[(size_t)row * 256 + h * 32 + m] = acc0[r];
        op[(size_t)row * 256 + h * 32 + 16 + m] = acc1[r];
    }
}

// ---------------------------------------------------------------------------
extern "C" void kernel_launch(void* const* d_in, const int* in_sizes, int n_in,
                              void* d_out, int out_size, void* d_ws, size_t ws_size,
                              hipStream_t stream) {
    const float* h      = (const float*)d_in[0];  // [4,1024,256]
    const float* adj    = (const float*)d_in[1];  // [4,1024,1024,1]
    const float* W      = (const float*)d_in[2];  // [256,256]
    const float* attn_w = (const float*)d_in[3];  // [64]
    float* out = (float*)d_out;                   // [4,1024,256]

    float* ws = (float*)d_ws;
    float* g    = ws;                     // 1,048,576 f
    float* EFi  = g + NROW * 256;         // 65,536 f
    float* EFj  = EFi + NROW * 16;        // 65,536 f
    float* EFjt = EFj + NROW * 16;        // 65,536 f  [b][h][{E,F}][n]
    float* ps   = EFjt + NROW * 16;       // 262,144 f
    short* Gt   = (short*)(ps + 8 * NROW * 8);  // 2,097,152 shorts (4MB)

    k_gemm_ei<<<NROW / 8, 256, 0, stream>>>(h, W, attn_w, g, EFi, EFj, EFjt);
    k_s<<<512, 256, 0, stream>>>(adj, EFi, EFj, ps);
    k_prep<<<256, 256, 0, stream>>>(ps, g, Gt);
    k_out_mfma<<<512, 256, 0, stream>>>(adj, Gt, EFi, EFjt, out);
}

// Round 2
// 122.150 us; speedup vs baseline: 1.0188x; 1.0188x over previous
//
#include <hip/hip_runtime.h>
#include <math.h>

#define BB 4
#define NN 1024
#define HH 8
#define NROW (BB*NN)  // 4096

typedef short s8v __attribute__((ext_vector_type(8)));
typedef float f4v __attribute__((ext_vector_type(4)));

__device__ __forceinline__ short bf16rne(float f) {
    unsigned u = __float_as_uint(f);
    u += 0x7FFF + ((u >> 16) & 1u);
    return (short)(u >> 16);
}
__device__ __forceinline__ unsigned pk2(float a, float b) {
    return ((unsigned)(unsigned short)bf16rne(a)) |
           (((unsigned)(unsigned short)bf16rne(b)) << 16);
}

// ---------------------------------------------------------------------------
// K1: g = h@W (8 rows/block, 512 blocks).
//  - Writes Gt = bf16(g) DIRECTLY (unnormalized; per-j softmax scale 1/D is
//    folded into k_out's staging instead — softmax is over axis i, so D
//    depends only on (b,j,h) and commutes into the per-j E/F tables).
//  - Writes exp tables for the separable-max trick:
//      exp(lrelu(ei+ej)) == max(exp(ei)*exp(ej), exp(.2ei)*exp(.2ej))
//    EFi:  [(b*N+n)*16 + 2h + {0,1}] = {exp(e_i), exp(.2 e_i)}
//    EFjt: [((b*8+h)*2 + {0,1})*N + n] (transposed, for k_den/k_out)
//  - Zeroes Dt (denominator accumulator) so k_den can atomicAdd.
// ---------------------------------------------------------------------------
__global__ __launch_bounds__(256) void k_gemm_ei(const float* __restrict__ hm,
                                                 const float* __restrict__ W,
                                                 const float* __restrict__ aw,
                                                 short* __restrict__ Gt,
                                                 float* __restrict__ EFi,
                                                 float* __restrict__ EFjt,
                                                 float* __restrict__ Dt) {
    __shared__ __align__(16) float hs[8][256];
    __shared__ float aws[64];
    const int row0 = blockIdx.x * 8;
    const int t = threadIdx.x;
    if (t < 64) {
        aws[t] = aw[t];
        Dt[blockIdx.x * 64 + t] = 0.f;  // 512 blocks x 64 = 32768 = |Dt|
    }
    const float4* h4 = (const float4*)(hm + row0 * 256);
    float4* hs4 = (float4*)&hs[0][0];
    hs4[t] = h4[t];
    hs4[t + 256] = h4[t + 256];
    __syncthreads();

    float acc[8];
#pragma unroll
    for (int r = 0; r < 8; ++r) acc[r] = 0.f;
    for (int k4 = 0; k4 < 64; ++k4) {
        const float w0 = W[(4 * k4 + 0) * 256 + t];
        const float w1 = W[(4 * k4 + 1) * 256 + t];
        const float w2 = W[(4 * k4 + 2) * 256 + t];
        const float w3 = W[(4 * k4 + 3) * 256 + t];
#pragma unroll
        for (int r = 0; r < 8; ++r) {
            const float4 hv = *(const float4*)&hs[r][4 * k4];  // broadcast read
            acc[r] = fmaf(hv.x, w0, acc[r]);
            acc[r] = fmaf(hv.y, w1, acc[r]);
            acc[r] = fmaf(hv.z, w2, acc[r]);
            acc[r] = fmaf(hv.w, w3, acc[r]);
        }
    }
    const int d = t & 31, hh = t >> 5;
    const int b = row0 >> 10;

    // ---- Gt[b][h][jt(32)][d(32)][jj(32)] = bf16(g), 8 consecutive j per thread
    {
        const int n0 = row0 & (NN - 1);
        short* dst = Gt + ((size_t)((b * 8 + hh) * 32 + (n0 >> 5))) * 1024 +
                     d * 32 + (n0 & 31);
        uint4 w;
        w.x = pk2(acc[0], acc[1]);
        w.y = pk2(acc[2], acc[3]);
        w.z = pk2(acc[4], acc[5]);
        w.w = pk2(acc[6], acc[7]);
        *(uint4*)dst = w;
    }

    // ---- e_i / e_j exp tables
#pragma unroll
    for (int r = 0; r < 8; ++r) {
        float vi = acc[r] * aws[d];
        float vj = acc[r] * aws[32 + d];
#pragma unroll
        for (int mm = 1; mm < 32; mm <<= 1) {
            vi += __shfl_xor(vi, mm);
            vj += __shfl_xor(vj, mm);
        }
        if (d == 0) {
            const int row = row0 + r;
            const int n = row & (NN - 1);
            *(float2*)&EFi[(size_t)row * 16 + hh * 2] =
                make_float2(__expf(vi), __expf(0.2f * vi));
            EFjt[((size_t)(b * 8 + hh) * 2 + 0) * NN + n] = __expf(vj);
            EFjt[((size_t)(b * 8 + hh) * 2 + 1) * NN + n] = __expf(0.2f * vj);
        }
    }
}

// ---------------------------------------------------------------------------
// K2: denominator D[b,j,h] += sum over i-chunk of adj[b,i,j]*max(Ei*Ej,Fi*Fj).
// 512 blocks = b x 16 j-chunks x 8 i-chunks; hardware f32 atomics (<=8-way
// contention per address). Replaces the old ps-chunk buffer + k_prep pass.
// ---------------------------------------------------------------------------
__global__ __launch_bounds__(256) void k_den(const float* __restrict__ adj,
                                             const float* __restrict__ EFi,
                                             const float* __restrict__ EFjt,
                                             float* __restrict__ Dt) {
    __shared__ __align__(16) float eis[128 * 16];  // 8KB: {E,F} x 8h per i
    __shared__ float sp[4][8][64];
    const int bx = blockIdx.x;
    const int b = bx >> 7, jc = (bx >> 3) & 15, ic = bx & 7;
    const int j0 = jc * 64, i0 = ic * 128;
    const int t = threadIdx.x;

    const float4* src4 = (const float4*)(EFi + (size_t)(b * NN + i0) * 16);
    ((float4*)eis)[t] = src4[t];
    ((float4*)eis)[t + 256] = src4[t + 256];

    const int ii = t >> 6, jj = t & 63;
    // per-thread E/F for its j column, all 8 heads (coalesced rows of EFjt)
    const float* ejb = EFjt + (size_t)b * 16 * NN + j0 + jj;
    const float ejE0 = ejb[0 * NN],  ejF0 = ejb[1 * NN];
    const float ejE1 = ejb[2 * NN],  ejF1 = ejb[3 * NN];
    const float ejE2 = ejb[4 * NN],  ejF2 = ejb[5 * NN];
    const float ejE3 = ejb[6 * NN],  ejF3 = ejb[7 * NN];
    const float ejE4 = ejb[8 * NN],  ejF4 = ejb[9 * NN];
    const float ejE5 = ejb[10 * NN], ejF5 = ejb[11 * NN];
    const float ejE6 = ejb[12 * NN], ejF6 = ejb[13 * NN];
    const float ejE7 = ejb[14 * NN], ejF7 = ejb[15 * NN];
    __syncthreads();

    float s0 = 0.f, s1 = 0.f, s2 = 0.f, s3 = 0.f;
    float s4 = 0.f, s5 = 0.f, s6 = 0.f, s7 = 0.f;
    const float* adjp = adj + (size_t)b * NN * NN + j0 + jj;
    for (int i = ii; i < 128; i += 4) {
        const float a = adjp[(size_t)(i0 + i) * NN];
        const float4 x0 = *(const float4*)&eis[i * 16];      // broadcast reads
        const float4 x1 = *(const float4*)&eis[i * 16 + 4];
        const float4 x2 = *(const float4*)&eis[i * 16 + 8];
        const float4 x3 = *(const float4*)&eis[i * 16 + 12];
        s0 = fmaf(a, fmaxf(x0.x * ejE0, x0.y * ejF0), s0);
        s1 = fmaf(a, fmaxf(x0.z * ejE1, x0.w * ejF1), s1);
        s2 = fmaf(a, fmaxf(x1.x * ejE2, x1.y * ejF2), s2);
        s3 = fmaf(a, fmaxf(x1.z * ejE3, x1.w * ejF3), s3);
        s4 = fmaf(a, fmaxf(x2.x * ejE4, x2.y * ejF4), s4);
        s5 = fmaf(a, fmaxf(x2.z * ejE5, x2.w * ejF5), s5);
        s6 = fmaf(a, fmaxf(x3.x * ejE6, x3.y * ejF6), s6);
        s7 = fmaf(a, fmaxf(x3.z * ejE7, x3.w * ejF7), s7);
    }
    sp[ii][0][jj] = s0; sp[ii][1][jj] = s1; sp[ii][2][jj] = s2; sp[ii][3][jj] = s3;
    sp[ii][4][jj] = s4; sp[ii][5][jj] = s5; sp[ii][6][jj] = s6; sp[ii][7][jj] = s7;
    __syncthreads();
#pragma unroll
    for (int k = 0; k < 2; ++k) {
        const int idx = t * 2 + k;
        const int jjo = idx >> 3, hq = idx & 7;
        const float sv =
            sp[0][hq][jjo] + sp[1][hq][jjo] + sp[2][hq][jjo] + sp[3][hq][jjo];
        unsafeAtomicAdd(&Dt[(size_t)(b * 8 + hq) * NN + j0 + jjo], sv);
    }
}

// ---------------------------------------------------------------------------
// K3: MFMA contraction. 512 blocks = (h-half, b, i-tile16); 4 waves, 1 head
// each. A generated in registers in A-frag layout (m=lane&15, k=quad*8+e):
//   A[i,j] = adj * max(Ei*(Ej/D), Fi*(Fj/D))   (softmax weight, <=1)
// The per-j 1/D scale is applied ONCE at staging time (E'/F' = E/D, F/D) so
// the inner loop is unchanged. B = bf16(g) unnormalized; direct store.
// All tiles in NAMED regs (scratch fix preserved).
// ---------------------------------------------------------------------------
__global__ __launch_bounds__(256) void k_out_mfma(const float* __restrict__ adj,
                                                  const short* __restrict__ Gt,
                                                  const float* __restrict__ EFi,
                                                  const float* __restrict__ EFjt,
                                                  const float* __restrict__ Dt,
                                                  float* __restrict__ out) {
    __shared__ short gts[4][4][32][40];  // 40KB: [h-local][jt-local][d][jj+pad]
    __shared__ float ejt[4][2][128];     // 4KB: [h-local][{E,F}/D][j in superstep]
    const int bx = blockIdx.x;
    const int hs = bx >> 8, b = (bx >> 6) & 3, i0 = (bx & 63) * 16;
    const int t = threadIdx.x;
    const int wave = t >> 6, lane = t & 63;
    const int m = lane & 15, q = lane >> 4;
    const int h = hs * 4 + wave;  // this wave's head

    const float2 eif = *(const float2*)&EFi[(size_t)(b * NN + i0 + m) * 16 + h * 2];
    const float EiV = eif.x, FiV = eif.y;
    f4v acc0 = {0.f, 0.f, 0.f, 0.f}, acc1 = {0.f, 0.f, 0.f, 0.f};

    const float* adjrow = adj + (size_t)b * NN * NN + (size_t)(i0 + m) * NN;
    const float4* gtg4 = (const float4*)Gt;  // 8 shorts per float4
    const float4* ejt4 = (const float4*)(EFjt + (size_t)b * 8 * 2 * NN);
    const float4* dt4  = (const float4*)(Dt + (size_t)b * 8 * NN);

    for (int s = 0; s < 8; ++s) {
        // ---- issue Gt loads (named regs g0..g7) + adj loads (a0..a7) + ej
        float4 g0, g1, g2, g3, g4, g5, g6, g7;
#define LG(k)                                                                     \
        {                                                                         \
            const int u = t + 256 * (k);                                          \
            g##k = gtg4[(size_t)(b * 8 + hs * 4 + (u >> 9)) * 4096 + s * 512 +    \
                        (u & 511)];                                               \
        }
        LG(0) LG(1) LG(2) LG(3) LG(4) LG(5) LG(6) LG(7)
#undef LG
        f4v a0, a1, a2, a3, a4, a5, a6, a7;
#define LA(k2, lt, half)                                                          \
        a##k2 = *(const f4v*)&adjrow[s * 128 + (lt) * 32 + q * 8 + (half) * 4];
        LA(0, 0, 0) LA(1, 0, 1) LA(2, 1, 0) LA(3, 1, 1)
        LA(4, 2, 0) LA(5, 2, 1) LA(6, 3, 0) LA(7, 3, 1)
#undef LA
        // all 256 threads: one float4 of EFjt ({E,F} rows x 4 heads x 32 f4),
        // scaled by the per-(j,h) softmax denominator at staging time.
        float4 ev =
            ejt4[(size_t)((hs * 4 + (t >> 6)) * 2 + ((t >> 5) & 1)) * 256 +
                 s * 32 + (t & 31)];
        const float4 dv = dt4[(size_t)(hs * 4 + (t >> 6)) * 256 + s * 32 + (t & 31)];
        ev.x /= dv.x; ev.y /= dv.y; ev.z /= dv.z; ev.w /= dv.w;
        __syncthreads();  // prior super's LDS reads done
#define SG(k)                                                                     \
        {                                                                         \
            const int u = t + 256 * (k);                                          \
            char* dstp = (char*)gts + (u >> 9) * 10240 + ((u >> 7) & 3) * 2560 +  \
                         ((u >> 2) & 31) * 80 + (u & 3) * 16;                     \
            *(float4*)dstp = g##k;                                                \
        }
        SG(0) SG(1) SG(2) SG(3) SG(4) SG(5) SG(6) SG(7)
#undef SG
        *(float4*)&ejt[t >> 6][(t >> 5) & 1][(t & 31) * 4] = ev;
        __syncthreads();  // LDS tile visible

        // ---- compute: 4 j-steps of 32, A built in named regs only
#define LT(lt, aA, aB)                                                            \
        {                                                                         \
            const f4v ejA = *(const f4v*)&ejt[wave][0][(lt) * 32 + q * 8];        \
            const f4v ejB = *(const f4v*)&ejt[wave][0][(lt) * 32 + q * 8 + 4];    \
            const f4v fjA = *(const f4v*)&ejt[wave][1][(lt) * 32 + q * 8];        \
            const f4v fjB = *(const f4v*)&ejt[wave][1][(lt) * 32 + q * 8 + 4];    \
            const float p0 = aA[0] * fmaxf(EiV * ejA[0], FiV * fjA[0]);           \
            const float p1 = aA[1] * fmaxf(EiV * ejA[1], FiV * fjA[1]);           \
            const float p2 = aA[2] * fmaxf(EiV * ejA[2], FiV * fjA[2]);           \
            const float p3 = aA[3] * fmaxf(EiV * ejA[3], FiV * fjA[3]);           \
            const float p4 = aB[0] * fmaxf(EiV * ejB[0], FiV * fjB[0]);           \
            const float p5 = aB[1] * fmaxf(EiV * ejB[1], FiV * fjB[1]);           \
            const float p6 = aB[2] * fmaxf(EiV * ejB[2], FiV * fjB[2]);           \
            const float p7 = aB[3] * fmaxf(EiV * ejB[3], FiV * fjB[3]);           \
            unsigned w0, w1, w2, w3;                                              \
            asm("v_cvt_pk_bf16_f32 %0, %1, %2" : "=v"(w0) : "v"(p0), "v"(p1));    \
            asm("v_cvt_pk_bf16_f32 %0, %1, %2" : "=v"(w1) : "v"(p2), "v"(p3));    \
            asm("v_cvt_pk_bf16_f32 %0, %1, %2" : "=v"(w2) : "v"(p4), "v"(p5));    \
            asm("v_cvt_pk_bf16_f32 %0, %1, %2" : "=v"(w3) : "v"(p6), "v"(p7));    \
            union { unsigned u[4]; s8v v; } Au;                                   \
            Au.u[0] = w0; Au.u[1] = w1; Au.u[2] = w2; Au.u[3] = w3;               \
            const s8v A = Au.v;                                                   \
            const s8v B0 = *(const s8v*)&gts[wave][lt][m][q * 8];                 \
            const s8v B1 = *(const s8v*)&gts[wave][lt][m + 16][q * 8];            \
            acc0 = __builtin_amdgcn_mfma_f32_16x16x32_bf16(A, B0, acc0, 0, 0, 0); \
            acc1 = __builtin_amdgcn_mfma_f32_16x16x32_bf16(A, B1, acc1, 0, 0, 0); \
        }
        LT(0, a0, a1) LT(1, a2, a3) LT(2, a4, a5) LT(3, a6, a7)
#undef LT
    }

    // ---- epilogue: C layout col=lane&15, row=quad*4+reg (already normalized)
    float* op = out + (size_t)(b * NN + i0) * 256;
#pragma unroll
    for (int r = 0; r < 4; ++r) {
        const int row = q * 4 + r;
        op[(size_t)row * 256 + h * 32 + m] = acc0[r];
        op[(size_t)row * 256 + h * 32 + 16 + m] = acc1[r];
    }
}

// ---------------------------------------------------------------------------
extern "C" void kernel_launch(void* const* d_in, const int* in_sizes, int n_in,
                              void* d_out, int out_size, void* d_ws, size_t ws_size,
                              hipStream_t stream) {
    const float* h      = (const float*)d_in[0];  // [4,1024,256]
    const float* adj    = (const float*)d_in[1];  // [4,1024,1024,1]
    const float* W      = (const float*)d_in[2];  // [256,256]
    const float* attn_w = (const float*)d_in[3];  // [64]
    float* out = (float*)d_out;                   // [4,1024,256]

    float* ws = (float*)d_ws;
    short* Gt   = (short*)ws;              // 2,097,152 shorts (4MB) = 1,048,576 f
    float* EFi  = ws + 1048576;            // 65,536 f
    float* EFjt = EFi + NROW * 16;         // 65,536 f  [b][h][{E,F}][n]
    float* Dt   = EFjt + NROW * 16;        // 32,768 f  [b][h][n]

    k_gemm_ei<<<NROW / 8, 256, 0, stream>>>(h, W, attn_w, Gt, EFi, EFjt, Dt);
    k_den<<<512, 256, 0, stream>>>(adj, EFi, EFjt, Dt);
    k_out_mfma<<<512, 256, 0, stream>>>(adj, Gt, EFi, EFjt, Dt, out);
}